// Round 13
// baseline (713.122 us; speedup 1.0000x reference)
//
#include <hip/hip_runtime.h>
#include <hip/hip_fp16.h>

typedef _Float16 f16;
typedef __attribute__((ext_vector_type(4))) _Float16 f16x4;
typedef __attribute__((ext_vector_type(8))) _Float16 f16x8;
typedef __attribute__((ext_vector_type(4))) float f32x4;

#define MFMA_F16(a,b,c) __builtin_amdgcn_mfma_f32_16x16x32_f16((a),(b),(c),0,0,0)

// async 16B/lane global->LDS DMA; global addr per-lane, LDS base wave-uniform
__device__ __forceinline__ void gl_lds16(const f16* g, f16* l) {
  __builtin_amdgcn_global_load_lds(
      (const __attribute__((address_space(1))) unsigned int*)g,
      (__attribute__((address_space(3))) unsigned int*)l, 16, 0, 0);
}

// ---------------------------------------------------------------------------
// Fragment-chunk packing (all DMA-ready, 1KB contiguous chunks):
//  input pack (x/W, [rows][256]): per 128-row tile, chunk (rt,ks8) idx rt*8+ks8
//  Q workspace (per b,h; 16 T-tiles of 64 seq x 128 k): chunk (jt,ks) idx
//    jt*4+ks: lane(q,c): [seq=T*64+jt*16+c][k=ks*32+q*8]
//  K workspace: SAME chunk geometry but kv slots PERMUTED within each 64-tile:
//    slot jt*16+quad*4+r holds ACTUAL kv (jt>>1)*32+quad*8+(jt&1)*4+r (pi).
//    => QK's C-layout lands P in exactly PV's A-operand order: pf[ks] =
//    {pk[2ks], pk[2ks+1]} in-register. No Ps LDS roundtrip (R13).
//  V workspace: chunk (ct,ks2) idx ct*2+ks2: lane(q,c): [d=ct*16+c][kv=T*64+ks2*32+q*8]
//  Eb pack (pack_eb -> d_out): f16(exp(B)), pi-matched: slab value j covers
//    col t*64 + h*32 + quad*8 + j (h=0/1 slab). Attn-side indexing unchanged.
// HISTORY:
//  R3 setprio -37%; R4 spills; R6 hi-occ thrash; R7 probe: VMEM-bound;
//  R8 T14 null. LAW: attn time ~ VMEM bytes/CU / rate; rate ~12.8 B/cy at
//  2 blocks/CU, only 9.4 at 1 block/CU (R12). R9 Eb: 117->99.7. R12 256-row
//  tile: 99.7->92.7 (under-delivered: 1 block/CU). R13: delete Ps via K-perm
//  -> LDS 96->64KB -> 2 blocks/CU at amplification 4.
// ---------------------------------------------------------------------------

// ---------------------------------------------------------------------------
// Pack pass: fp32 row-major -> f16 fragment-chunk tiles (coalesced in+out).
// ---------------------------------------------------------------------------
__global__ __launch_bounds__(256) void conv_pack(
    const float* __restrict__ x1, const float* __restrict__ x2,
    const float* __restrict__ wq, const float* __restrict__ wk,
    const float* __restrict__ wv,
    f16* __restrict__ x1p, f16* __restrict__ x2p, f16* __restrict__ wp) {
  __shared__ f16 S[128][264];
  const int id = blockIdx.x, tid = threadIdx.x;
  const float* src;
  f16* dst;
  if (id < 128) {
    src = x1 + (size_t)id * 32768; dst = x1p + (size_t)id * 32768;
  } else if (id < 256) {
    src = x2 + (size_t)(id - 128) * 32768; dst = x2p + (size_t)(id - 128) * 32768;
  } else {
    const int wsel = (id - 256) >> 3, wt = (id - 256) & 7;
    const float* wsrc = (wsel == 0) ? wq : (wsel == 1) ? wk : wv;
    src = wsrc + (size_t)wt * 32768;
    dst = wp + (size_t)wsel * 262144 + (size_t)wt * 32768;
  }
#pragma unroll 8
  for (int i = 0; i < 32; i++) {
    int f = i * 256 + tid;           // 8192 float4s = 128 rows x 64
    int row = f >> 6, c4 = f & 63;
    float4 v = *(const float4*)(src + (size_t)row * 256 + c4 * 4);
    f16x4 hh; hh[0] = (f16)v.x; hh[1] = (f16)v.y; hh[2] = (f16)v.z; hh[3] = (f16)v.w;
    *(f16x4*)&S[row][c4 * 4] = hh;
  }
  __syncthreads();
#pragma unroll 8
  for (int i = 0; i < 16; i++) {
    int u = i * 256 + tid;           // 4096 b128 units
    int chunk = u >> 6, l2 = u & 63;
    int q = l2 >> 4, c = l2 & 15;
    int row = (chunk >> 3) * 16 + c, k = (chunk & 7) * 32 + q * 8;
    f16x8 v = *(const f16x8*)&S[row][k];
    *(f16x8*)(dst + (size_t)u * 8) = v;
  }
}

// ---------------------------------------------------------------------------
// Eb pack: f16(exp(B)), pi-matched contiguous columns (see header).
// Grid 128 (id = mt128*16 + t). Output -> d_out scratch (2 MiB).
// ---------------------------------------------------------------------------
__global__ __launch_bounds__(256) void pack_eb(
    const float* __restrict__ Bm, f16* __restrict__ Ebp) {
  __shared__ float S[128][68];   // +4 pad
  const int id = blockIdx.x, tid = threadIdx.x;
  const int mt = id >> 4, t = id & 15;
  const int m0 = mt * 128, n0 = t * 64;
#pragma unroll
  for (int i = 0; i < 8; i++) {
    int f = i * 256 + tid;         // 2048 float4s = 128 rows x 16
    int r = f >> 4, c4 = f & 15;
    float4 v = *(const float4*)(Bm + (size_t)(m0 + r) * 1024 + n0 + c4 * 4);
    *(float4*)&S[r][c4 * 4] = v;
  }
  __syncthreads();
#pragma unroll
  for (int i = 0; i < 2; i++) {
    int s = i * 256 + tid;         // 512 lane-slots (8 qcw x 64 lanes)
    int qcw = s >> 6, lane = s & 63;
    int col = lane & 15, quad = lane >> 4;
    int row = qcw * 16 + col;
    f16x8 h0, h1;
#pragma unroll
    for (int j = 0; j < 8; j++)
      h0[j] = (f16)__expf(S[row][quad * 8 + j]);          // kv 0..31 half
#pragma unroll
    for (int j = 0; j < 8; j++)
      h1[j] = (f16)__expf(S[row][32 + quad * 8 + j]);     // kv 32..63 half
    // lane-contiguous: h slabs of 512 f16 (64 lanes x 8)
    f16* out = Ebp + ((size_t)(id * 8 + qcw) * 2) * 512 + lane * 8;
    *(f16x8*)out = h0;
    *(f16x8*)(out + 512) = h1;
  }
}

// ---------------------------------------------------------------------------
// QKV GEMM v5: pure-DMA staging. grid (128 xt, 8 h, 3 z). BM=128 x BN=128 x
// BK=64, double-buffered, one barrier/iter. 512 thr = 8 waves.
// z==1 (K) epilogue writes PERMUTED kv slots (pi^-1) so attn's QK output is
// PV-ready in-register (see header).
// ---------------------------------------------------------------------------
__global__ __launch_bounds__(512) __attribute__((amdgpu_waves_per_eu(4, 4)))
void gemm_qkv(const f16* __restrict__ x1p, const f16* __restrict__ x2p,
              const f16* __restrict__ wp,
              const float* __restrict__ wqb, const float* __restrict__ wkb,
              const float* __restrict__ wvb,
              f16* __restrict__ Qp, f16* __restrict__ Kp, f16* __restrict__ Vp,
              float qscale) {
  __shared__ f16 Wl[2][8192];
  __shared__ f16 Xl[2][8192];
  const int z = blockIdx.z;
  const f16* Xp = (z == 0) ? x1p : x2p;
  const float* bias = (z == 0) ? wqb : (z == 1) ? wkb : wvb;
  f16* outp = (z == 0) ? Qp : (z == 1) ? Kp : Vp;
  const float sc = (z == 0) ? qscale : 1.0f;

  const int tid = threadIdx.x, lane = tid & 63, wid = tid >> 6;
  const int col = lane & 15, quad = lane >> 4;
  const int xt = blockIdx.x, h = blockIdx.y;
  const int wr = wid >> 2, xc = wid & 3;  // wave M-group / N-group
  const f16* Xb = Xp + (size_t)xt * 32768;
  const f16* Wb = wp + (size_t)z * 262144 + (size_t)h * 32768;

#define QISSUE(T, bufi)                                                   \
  {                                                                       \
    _Pragma("unroll") for (int j = 0; j < 2; j++) {                       \
      int lc = wid * 2 + j;                                               \
      int rt = lc >> 1, ksl = lc & 1;                                     \
      gl_lds16(Wb + (size_t)((rt * 8 + (T) * 2 + ksl) << 9) + lane * 8,   \
               &Wl[bufi][lc * 512]);                                      \
      gl_lds16(Xb + (size_t)((rt * 8 + (T) * 2 + ksl) << 9) + lane * 8,   \
               &Xl[bufi][lc * 512]);                                      \
    }                                                                     \
  }

  QISSUE(0, 0);
  QISSUE(1, 1);

  f32x4 acc[4][2];
#pragma unroll
  for (int i = 0; i < 4; i++)
#pragma unroll
    for (int j = 0; j < 2; j++) acc[i][j] = (f32x4){0.f, 0.f, 0.f, 0.f};

  __syncthreads();

  for (int t = 0; t < 4; ++t) {
    const int buf = t & 1;
    const f16* Ra = (z == 2) ? Xl[buf] : Wl[buf];  // A-operand (C rows)
    const f16* Cb = (z == 2) ? Wl[buf] : Xl[buf];  // B-operand (C cols)
#pragma unroll
    for (int ksl = 0; ksl < 2; ksl++) {
      f16x8 af[4], bf[2];
#pragma unroll
      for (int i = 0; i < 4; i++)
        af[i] = *(const f16x8*)&Ra[((wr * 4 + i) * 2 + ksl) * 512 + lane * 8];
#pragma unroll
      for (int j = 0; j < 2; j++)
        bf[j] = *(const f16x8*)&Cb[((xc * 2 + j) * 2 + ksl) * 512 + lane * 8];
#pragma unroll
      for (int i = 0; i < 4; i++)
#pragma unroll
        for (int j = 0; j < 2; j++) acc[i][j] = MFMA_F16(af[i], bf[j], acc[i][j]);
    }
    __syncthreads();
    if (t + 2 < 4) QISSUE(t + 2, buf);
  }

  if (z < 2) {
    // C rows = hd (k-runs over r), cols = seq -> Q/K packed chunks.
    // K (z==1): seq slot permuted: slot' = pi^-1(kv6).
#pragma unroll
    for (int i = 0; i < 4; i++) {
      const int k0h = wr * 64 + i * 16 + quad * 4;
      float4 bq = *(const float4*)(bias + h * 128 + k0h);
      const int ks2 = k0h >> 5, q2 = (k0h >> 3) & 3, lo = k0h & 7;
#pragma unroll
      for (int j = 0; j < 2; j++) {
        const int bn2 = xt * 128 + xc * 32 + j * 16 + col;
        const int b = bn2 >> 10, n2 = bn2 & 1023;
        const int T = n2 >> 6;
        int jt, c2;
        if (z == 1) {
          jt = 2 * ((n2 >> 5) & 1) + ((n2 >> 2) & 1);
          c2 = ((n2 >> 3) & 3) * 4 + (n2 & 3);
        } else {
          jt = (n2 >> 4) & 3;
          c2 = n2 & 15;
        }
        f16x4 pk;
#pragma unroll
        for (int r = 0; r < 4; r++)
          pk[r] = (f16)((acc[i][j][r] + ((const float*)&bq)[r]) * sc);
        *(f16x4*)(outp + (size_t)(b * 8 + h) * 131072 + T * 8192 +
                  (jt * 4 + ks2) * 512 + (q2 * 16 + c2) * 8 + lo) = pk;
      }
    }
  } else {
#pragma unroll
    for (int j = 0; j < 2; j++) {
      const int d = xc * 32 + j * 16 + col;
      const float bv = bias[h * 128 + d];
      const int ct = d >> 4, cc = d & 15;
#pragma unroll
      for (int i = 0; i < 4; i++) {
        const int bn2 = xt * 128 + wr * 64 + i * 16 + quad * 4;
        const int b = bn2 >> 10, n2 = bn2 & 1023;
        const int T = n2 >> 6, kv6 = n2 & 63;
        const int ks2 = kv6 >> 5, qv = (kv6 >> 3) & 3, jj = kv6 & 7;
        f16x4 pk;
#pragma unroll
        for (int r = 0; r < 4; r++) pk[r] = (f16)(acc[i][j][r] + bv);
        *(f16x4*)(outp + (size_t)(b * 8 + h) * 131072 + T * 8192 +
                  (ct * 2 + ks2) * 512 + (qv * 16 + cc) * 8 + jj) = pk;
      }
    }
  }
}

// ---------------------------------------------------------------------------
// Proj GEMM: out[16384,128] = A[16384,1024](f16) @ W[128,1024]^T + b, fp32.
// ---------------------------------------------------------------------------
__global__ __launch_bounds__(256) void gemm_proj(const f16* __restrict__ A,
                                                 const float* __restrict__ W,
                                                 const float* __restrict__ bias,
                                                 float* __restrict__ out) {
  constexpr int LD = 72;
  __shared__ f16 As[64][LD];
  __shared__ f16 Bs[64][LD];
  const int tid = threadIdx.x, lane = tid & 63, wid = tid >> 6;
  const int col = lane & 15, quad = lane >> 4;
  const int wm = (wid >> 1) * 32, wn = (wid & 1) * 32;
  const int m0 = blockIdx.x * 64, n0 = blockIdx.y * 64;

  f32x4 acc[2][2];
#pragma unroll
  for (int i = 0; i < 2; i++)
#pragma unroll
    for (int j = 0; j < 2; j++) acc[i][j] = (f32x4){0.f, 0.f, 0.f, 0.f};

  for (int kt = 0; kt < 16; ++kt) {
    const int k0 = kt * 64;
#pragma unroll
    for (int i = 0; i < 2; i++) {
      int f = i * 256 + tid;
      int r = f >> 3, ch = f & 7;
      *(f16x8*)&As[r][ch * 8] = *(const f16x8*)(A + (size_t)(m0 + r) * 1024 + k0 + ch * 8);
    }
#pragma unroll
    for (int i = 0; i < 4; i++) {
      int f = i * 256 + tid;
      int r = f >> 4, c4 = f & 15;
      float4 v = *(const float4*)(W + (size_t)(n0 + r) * 1024 + k0 + c4 * 4);
      f16x4 hh; hh[0] = (f16)v.x; hh[1] = (f16)v.y; hh[2] = (f16)v.z; hh[3] = (f16)v.w;
      *(f16x4*)&Bs[r][c4 * 4] = hh;
    }
    __syncthreads();
#pragma unroll
    for (int ks = 0; ks < 2; ks++) {
      f16x8 af[2], bf[2];
#pragma unroll
      for (int i = 0; i < 2; i++) af[i] = *(const f16x8*)&As[wm + i * 16 + col][ks * 32 + quad * 8];
#pragma unroll
      for (int j = 0; j < 2; j++) bf[j] = *(const f16x8*)&Bs[wn + j * 16 + col][ks * 32 + quad * 8];
#pragma unroll
      for (int i = 0; i < 2; i++)
#pragma unroll
        for (int j = 0; j < 2; j++) acc[i][j] = MFMA_F16(af[i], bf[j], acc[i][j]);
    }
    __syncthreads();
  }
#pragma unroll
  for (int j = 0; j < 2; j++) {
    const int c = n0 + wn + j * 16 + col;
    const float bv = bias[c];
#pragma unroll
    for (int i = 0; i < 2; i++) {
      const int r0 = m0 + wm + i * 16 + quad * 4;
#pragma unroll
      for (int r = 0; r < 4; r++)
        out[(size_t)(r0 + r) * 128 + c] = acc[i][j][r] + bv;
    }
  }
}

// ---------------------------------------------------------------------------
// Fused attention v11 (R13): 512 thr = 8 waves x 32 q-rows = 256 q-rows/block,
// kv-tile 64, gl_lds double-buffer, Eb f16 exp-bias, NO Ps: K-perm makes the
// QK output PV-ready in-register (pf[ks] = {pk[2ks], pk[2ks+1]}).
// LDS = K 32K + V 32K = 64KB -> 2 blocks/CU (16 waves/CU, 4/SIMD).
// ---------------------------------------------------------------------------
__global__ __launch_bounds__(512) __attribute__((amdgpu_waves_per_eu(4)))
void attn_fused(const f16* __restrict__ Qp, const f16* __restrict__ Kp,
                const f16* __restrict__ Vp, const f16* __restrict__ Ebp,
                f16* __restrict__ O) {
  __shared__ f16 Ksl[2][8192];
  __shared__ f16 Vtl[2][8192];
  const int tid = threadIdx.x, lane = tid & 63, wid = tid >> 6;  // wid 0..7
  const int col = lane & 15, quad = lane >> 4;
  const int id = blockIdx.x;
  const int mt = (id >> 3) & 3;                       // 4 m-tiles of 256 rows
  const int bh = ((id >> 5) << 3) | (id & 7);         // b = id>>5, h = id&7
  const int b = bh >> 3, h = bh & 7;
  const int m0 = mt * 256;
  const int wm = wid * 32;  // wave's 32 q-rows within the 256-row tile

  const f16* Qb = Qp + (size_t)bh * 131072;
  const f16* Kb = Kp + (size_t)bh * 131072;
  const f16* Vb = Vp + (size_t)bh * 131072;
  // Eb base: 128-row tile index = mt*2 + (wid>>2); qcw = (wid&3)*2 + qc.
  const int tile128 = mt * 2 + (wid >> 2);
  const f16* Ebw = Ebp +
      (((size_t)tile128 * 16 * 8 + (wid & 3) * 2) * 2) * 512 + lane * 8;

  // waves 0-3 stage K chunks (4 each), waves 4-7 stage V chunks (4 each)
#define AISSUE(T, bufi)                                                       \
  {                                                                           \
    if (wid < 4) {                                                            \
      _Pragma("unroll") for (int j = 0; j < 4; j++)                           \
          gl_lds16(Kb + (size_t)(T) * 8192 + (wid * 4 + j) * 512 + lane * 8,  \
                   &Ksl[bufi][(wid * 4 + j) * 512]);                          \
    } else {                                                                  \
      _Pragma("unroll") for (int j = 0; j < 4; j++)                           \
          gl_lds16(Vb + (size_t)(T) * 8192 + ((wid - 4) * 4 + j) * 512 + lane * 8, \
                   &Vtl[bufi][((wid - 4) * 4 + j) * 512]);                    \
    }                                                                         \
  }

  AISSUE(0, 0);
  AISSUE(1, 1);

  f16x8 qf[2][4];
#pragma unroll
  for (int qc = 0; qc < 2; qc++) {
    const int m = m0 + wm + qc * 16;
    const int T = m >> 6, jt2 = (m >> 4) & 3;
#pragma unroll
    for (int ks = 0; ks < 4; ks++)
      qf[qc][ks] = *(const f16x8*)(Qb + T * 8192 + (jt2 * 4 + ks) * 512 + lane * 8);
  }

  f32x4 oacc[2][8];
  float l[2] = {0.f, 0.f};
#pragma unroll
  for (int qc = 0; qc < 2; qc++)
#pragma unroll
    for (int ct = 0; ct < 8; ct++) oacc[qc][ct] = (f32x4){0.f, 0.f, 0.f, 0.f};

  __syncthreads();

  for (int t = 0; t < 16; ++t) {
    const int buf = t & 1;

    // exp-bias: 4 lane-contiguous f16x8 loads (16B lane stride)
    f16x8 ebA[2], ebB[2];
    {
      const f16* Et = Ebw + (size_t)t * 8192;
      ebA[0] = *(const f16x8*)(Et);
      ebB[0] = *(const f16x8*)(Et + 512);
      ebA[1] = *(const f16x8*)(Et + 1024);
      ebB[1] = *(const f16x8*)(Et + 1536);
    }

    f32x4 s[2][4];
#pragma unroll
    for (int qc = 0; qc < 2; qc++)
#pragma unroll
      for (int jt = 0; jt < 4; jt++) s[qc][jt] = (f32x4){0.f, 0.f, 0.f, 0.f};
#pragma unroll
    for (int ks = 0; ks < 4; ks++) {
      f16x8 kf[4];
#pragma unroll
      for (int jt = 0; jt < 4; jt++)
        kf[jt] = *(const f16x8*)&Ksl[buf][(jt * 4 + ks) * 512 + lane * 8];
#pragma unroll
      for (int jt = 0; jt < 4; jt++)
#pragma unroll
        for (int qc = 0; qc < 2; qc++)
          s[qc][jt] = MFMA_F16(kf[jt], qf[qc][ks], s[qc][jt]);
    }

    // softmax numerator straight into PV A-fragments (K-perm: s[jt][r] is
    // actual kv (jt>>1)*32 + quad*8 + (jt&1)*4 + r).
    f16x8 pa[2][2];   // [qc][ks]: P[q=col][kv = ks*32 + quad*8 + 0..7]
#pragma unroll
    for (int qc = 0; qc < 2; qc++) {
#pragma unroll
      for (int jt = 0; jt < 4; jt++) {
        float p0, p1, p2, p3;
        if (jt < 2) {
          p0 = __expf(s[qc][jt][0]) * (float)ebA[qc][(jt & 1) * 4 + 0];
          p1 = __expf(s[qc][jt][1]) * (float)ebA[qc][(jt & 1) * 4 + 1];
          p2 = __expf(s[qc][jt][2]) * (float)ebA[qc][(jt & 1) * 4 + 2];
          p3 = __expf(s[qc][jt][3]) * (float)ebA[qc][(jt & 1) * 4 + 3];
        } else {
          p0 = __expf(s[qc][jt][0]) * (float)ebB[qc][(jt & 1) * 4 + 0];
          p1 = __expf(s[qc][jt][1]) * (float)ebB[qc][(jt & 1) * 4 + 1];
          p2 = __expf(s[qc][jt][2]) * (float)ebB[qc][(jt & 1) * 4 + 2];
          p3 = __expf(s[qc][jt][3]) * (float)ebB[qc][(jt & 1) * 4 + 3];
        }
        l[qc] += (p0 + p1) + (p2 + p3);
        f16x4 pk; pk[0] = (f16)p0; pk[1] = (f16)p1; pk[2] = (f16)p2; pk[3] = (f16)p3;
        ((f16x4*)&pa[qc][jt >> 1])[jt & 1] = pk;   // static idx (unrolled)
      }
    }

#pragma unroll
    for (int ks = 0; ks < 2; ks++) {
#pragma unroll
      for (int ct = 0; ct < 8; ct++) {
        f16x8 vf = *(const f16x8*)&Vtl[buf][(ct * 2 + ks) * 512 + lane * 8];
#pragma unroll
        for (int qc = 0; qc < 2; qc++)
          oacc[qc][ct] = MFMA_F16(pa[qc][ks], vf, oacc[qc][ct]);
      }
    }

    __syncthreads();
    if (t + 2 < 16) AISSUE(t + 2, buf);
  }

#pragma unroll
  for (int qc = 0; qc < 2; qc++) {
    float lw = l[qc];
    lw += __shfl_xor(lw, 16);
    lw += __shfl_xor(lw, 32);
    f16* Ob = O + ((size_t)(b * 1024 + m0 + wm + qc * 16)) * 1024 + h * 128;
#pragma unroll
    for (int r = 0; r < 4; r++) {
      const float lv = __shfl(lw, (lane & 48) | (quad * 4 + r));
      const float inv = 1.0f / lv;
#pragma unroll
      for (int ct = 0; ct < 8; ct++)
        Ob[(size_t)(quad * 4 + r) * 1024 + ct * 16 + col] = (f16)(oacc[qc][ct][r] * inv);
    }
  }
}

extern "C" void kernel_launch(void* const* d_in, const int* in_sizes, int n_in,
                              void* d_out, int out_size, void* d_ws, size_t ws_size,
                              hipStream_t stream) {
  (void)in_sizes; (void)n_in; (void)out_size; (void)ws_size;
  const float* x1  = (const float*)d_in[0];
  const float* x2  = (const float*)d_in[1];
  const float* Bm  = (const float*)d_in[2];
  const float* wq  = (const float*)d_in[3];
  const float* wqb = (const float*)d_in[4];
  const float* wk  = (const float*)d_in[5];
  const float* wkb = (const float*)d_in[6];
  const float* wv  = (const float*)d_in[7];
  const float* wvb = (const float*)d_in[8];
  const float* pw  = (const float*)d_in[9];
  const float* pb  = (const float*)d_in[10];
  float* out = (float*)d_out;

  const size_t MiB = 1024 * 1024;
  f16* Qp  = (f16*)d_ws;                            // 0..32 MiB
  f16* Kp  = (f16*)((char*)d_ws + 32 * MiB);        // 32..64
  f16* Vp  = (f16*)((char*)d_ws + 64 * MiB);        // 64..96
  f16* Ow  = (f16*)((char*)d_ws + 96 * MiB);        // 96..128 (attn output)
  // packed inputs: alive only conv->qkv, then overlaid by Ow
  f16* x1p = (f16*)((char*)d_ws + 96 * MiB);        // 8 MiB
  f16* x2p = (f16*)((char*)d_ws + 104 * MiB);       // 8 MiB
  f16* wp  = (f16*)((char*)d_ws + 112 * MiB);       // 1.5 MiB
  // Packed exp-bias in d_out's first 2 MiB (out is 8 MiB fp32): written by
  // pack_eb pre-attn, read by attn, overwritten by gemm_proj at the end.
  f16* Ebp = (f16*)d_out;

  const float scale = 0.0883883476483184f;  // 1/sqrt(128)
  conv_pack<<<dim3(280), dim3(256), 0, stream>>>(x1, x2, wq, wk, wv, x1p, x2p, wp);
  pack_eb<<<dim3(128), dim3(256), 0, stream>>>(Bm, Ebp);
  gemm_qkv<<<dim3(128, 8, 3), dim3(512), 0, stream>>>(x1p, x2p, wp, wqb, wkb, wvb,
                                                      Qp, Kp, Vp, scale);
  attn_fused<<<dim3(512), dim3(512), 0, stream>>>(Qp, Kp, Vp, Ebp, Ow);
  gemm_proj<<<dim3(256, 2), dim3(256), 0, stream>>>(Ow, pw, pb, out);
}

// Round 14
// 263.105 us; speedup vs baseline: 2.7104x; 2.7104x over previous
//
#include <hip/hip_runtime.h>
#include <hip/hip_fp16.h>

typedef _Float16 f16;
typedef __attribute__((ext_vector_type(4))) _Float16 f16x4;
typedef __attribute__((ext_vector_type(8))) _Float16 f16x8;
typedef __attribute__((ext_vector_type(4))) float f32x4;

#define MFMA_F16(a,b,c) __builtin_amdgcn_mfma_f32_16x16x32_f16((a),(b),(c),0,0,0)

// async 16B/lane global->LDS DMA; global addr per-lane, LDS base wave-uniform
__device__ __forceinline__ void gl_lds16(const f16* g, f16* l) {
  __builtin_amdgcn_global_load_lds(
      (const __attribute__((address_space(1))) unsigned int*)g,
      (__attribute__((address_space(3))) unsigned int*)l, 16, 0, 0);
}

// ---------------------------------------------------------------------------
// Fragment-chunk packing (all DMA-ready, 1KB contiguous chunks):
//  input pack (x/W, [rows][256]): per 128-row tile, chunk (rt,ks8) idx rt*8+ks8
//  Q workspace (per b,h; 16 T-tiles of 64 seq x 128 k): chunk (jt,ks) idx
//    jt*4+ks: lane(q,c): [seq=T*64+jt*16+c][k=ks*32+q*8]
//  K workspace: SAME chunk geometry but kv slots PERMUTED within each 64-tile:
//    slot jt*16+quad*4+r holds ACTUAL kv (jt>>1)*32+quad*8+(jt&1)*4+r (pi).
//    => QK's C-layout lands P in exactly PV's A-operand order: pa[ks] =
//    {pk[2ks], pk[2ks+1]} in-register. No Ps LDS roundtrip.
//  V workspace: chunk (ct,ks2) idx ct*2+ks2: lane(q,c): [d=ct*16+c][kv=T*64+ks2*32+q*8]
//  Eb pack (pack_eb -> d_out): f16(exp(B)), pi-matched: slab value j covers
//    col t*64 + h*32 + quad*8 + j (h=0/1 slab).
// HISTORY:
//  R3 setprio -37%; R4 spills; R6 hi-occ thrash; R7 probe: VMEM-bound;
//  R8 T14 null. LAW: attn time ~ VMEM bytes/CU / rate (~12.8 B/cy at 2
//  blocks/CU, ~9.4 at 1 block/CU). R9 Eb: 117->99.7. R12 256-row tile:
//  99.7->92.7. R13 K-perm no-Ps: ALGEBRA VERIFIED (passed, conflicts 2.1M->0)
//  but waves_per_eu(4) capped VGPR at 128 < ~170 live -> 64-VGPR megaspill
//  (WRITE 32MB->1.34GB, 529us). RULE: never tighten VGPR cap in the same
//  round as a state-adding structure change.
//  R14: launch_bounds(512,2) (256 cap, R12's proven config). 1 block/CU
//  accepted; 2-blocks/CU (needs <=128 VGPR diet) deferred.
// ---------------------------------------------------------------------------

// ---------------------------------------------------------------------------
// Pack pass: fp32 row-major -> f16 fragment-chunk tiles (coalesced in+out).
// ---------------------------------------------------------------------------
__global__ __launch_bounds__(256) void conv_pack(
    const float* __restrict__ x1, const float* __restrict__ x2,
    const float* __restrict__ wq, const float* __restrict__ wk,
    const float* __restrict__ wv,
    f16* __restrict__ x1p, f16* __restrict__ x2p, f16* __restrict__ wp) {
  __shared__ f16 S[128][264];
  const int id = blockIdx.x, tid = threadIdx.x;
  const float* src;
  f16* dst;
  if (id < 128) {
    src = x1 + (size_t)id * 32768; dst = x1p + (size_t)id * 32768;
  } else if (id < 256) {
    src = x2 + (size_t)(id - 128) * 32768; dst = x2p + (size_t)(id - 128) * 32768;
  } else {
    const int wsel = (id - 256) >> 3, wt = (id - 256) & 7;
    const float* wsrc = (wsel == 0) ? wq : (wsel == 1) ? wk : wv;
    src = wsrc + (size_t)wt * 32768;
    dst = wp + (size_t)wsel * 262144 + (size_t)wt * 32768;
  }
#pragma unroll 8
  for (int i = 0; i < 32; i++) {
    int f = i * 256 + tid;           // 8192 float4s = 128 rows x 64
    int row = f >> 6, c4 = f & 63;
    float4 v = *(const float4*)(src + (size_t)row * 256 + c4 * 4);
    f16x4 hh; hh[0] = (f16)v.x; hh[1] = (f16)v.y; hh[2] = (f16)v.z; hh[3] = (f16)v.w;
    *(f16x4*)&S[row][c4 * 4] = hh;
  }
  __syncthreads();
#pragma unroll 8
  for (int i = 0; i < 16; i++) {
    int u = i * 256 + tid;           // 4096 b128 units
    int chunk = u >> 6, l2 = u & 63;
    int q = l2 >> 4, c = l2 & 15;
    int row = (chunk >> 3) * 16 + c, k = (chunk & 7) * 32 + q * 8;
    f16x8 v = *(const f16x8*)&S[row][k];
    *(f16x8*)(dst + (size_t)u * 8) = v;
  }
}

// ---------------------------------------------------------------------------
// Eb pack: f16(exp(B)), pi-matched contiguous columns (see header).
// Grid 128 (id = mt128*16 + t). Output -> d_out scratch (2 MiB).
// ---------------------------------------------------------------------------
__global__ __launch_bounds__(256) void pack_eb(
    const float* __restrict__ Bm, f16* __restrict__ Ebp) {
  __shared__ float S[128][68];   // +4 pad
  const int id = blockIdx.x, tid = threadIdx.x;
  const int mt = id >> 4, t = id & 15;
  const int m0 = mt * 128, n0 = t * 64;
#pragma unroll
  for (int i = 0; i < 8; i++) {
    int f = i * 256 + tid;         // 2048 float4s = 128 rows x 16
    int r = f >> 4, c4 = f & 15;
    float4 v = *(const float4*)(Bm + (size_t)(m0 + r) * 1024 + n0 + c4 * 4);
    *(float4*)&S[r][c4 * 4] = v;
  }
  __syncthreads();
#pragma unroll
  for (int i = 0; i < 2; i++) {
    int s = i * 256 + tid;         // 512 lane-slots (8 qcw x 64 lanes)
    int qcw = s >> 6, lane = s & 63;
    int col = lane & 15, quad = lane >> 4;
    int row = qcw * 16 + col;
    f16x8 h0, h1;
#pragma unroll
    for (int j = 0; j < 8; j++)
      h0[j] = (f16)__expf(S[row][quad * 8 + j]);          // kv 0..31 half
#pragma unroll
    for (int j = 0; j < 8; j++)
      h1[j] = (f16)__expf(S[row][32 + quad * 8 + j]);     // kv 32..63 half
    // lane-contiguous: h slabs of 512 f16 (64 lanes x 8)
    f16* out = Ebp + ((size_t)(id * 8 + qcw) * 2) * 512 + lane * 8;
    *(f16x8*)out = h0;
    *(f16x8*)(out + 512) = h1;
  }
}

// ---------------------------------------------------------------------------
// QKV GEMM v5: pure-DMA staging. grid (128 xt, 8 h, 3 z). BM=128 x BN=128 x
// BK=64, double-buffered, one barrier/iter. 512 thr = 8 waves.
// z==1 (K) epilogue writes PERMUTED kv slots (pi^-1) so attn's QK output is
// PV-ready in-register (see header).
// ---------------------------------------------------------------------------
__global__ __launch_bounds__(512) __attribute__((amdgpu_waves_per_eu(4, 4)))
void gemm_qkv(const f16* __restrict__ x1p, const f16* __restrict__ x2p,
              const f16* __restrict__ wp,
              const float* __restrict__ wqb, const float* __restrict__ wkb,
              const float* __restrict__ wvb,
              f16* __restrict__ Qp, f16* __restrict__ Kp, f16* __restrict__ Vp,
              float qscale) {
  __shared__ f16 Wl[2][8192];
  __shared__ f16 Xl[2][8192];
  const int z = blockIdx.z;
  const f16* Xp = (z == 0) ? x1p : x2p;
  const float* bias = (z == 0) ? wqb : (z == 1) ? wkb : wvb;
  f16* outp = (z == 0) ? Qp : (z == 1) ? Kp : Vp;
  const float sc = (z == 0) ? qscale : 1.0f;

  const int tid = threadIdx.x, lane = tid & 63, wid = tid >> 6;
  const int col = lane & 15, quad = lane >> 4;
  const int xt = blockIdx.x, h = blockIdx.y;
  const int wr = wid >> 2, xc = wid & 3;  // wave M-group / N-group
  const f16* Xb = Xp + (size_t)xt * 32768;
  const f16* Wb = wp + (size_t)z * 262144 + (size_t)h * 32768;

#define QISSUE(T, bufi)                                                   \
  {                                                                       \
    _Pragma("unroll") for (int j = 0; j < 2; j++) {                       \
      int lc = wid * 2 + j;                                               \
      int rt = lc >> 1, ksl = lc & 1;                                     \
      gl_lds16(Wb + (size_t)((rt * 8 + (T) * 2 + ksl) << 9) + lane * 8,   \
               &Wl[bufi][lc * 512]);                                      \
      gl_lds16(Xb + (size_t)((rt * 8 + (T) * 2 + ksl) << 9) + lane * 8,   \
               &Xl[bufi][lc * 512]);                                      \
    }                                                                     \
  }

  QISSUE(0, 0);
  QISSUE(1, 1);

  f32x4 acc[4][2];
#pragma unroll
  for (int i = 0; i < 4; i++)
#pragma unroll
    for (int j = 0; j < 2; j++) acc[i][j] = (f32x4){0.f, 0.f, 0.f, 0.f};

  __syncthreads();

  for (int t = 0; t < 4; ++t) {
    const int buf = t & 1;
    const f16* Ra = (z == 2) ? Xl[buf] : Wl[buf];  // A-operand (C rows)
    const f16* Cb = (z == 2) ? Wl[buf] : Xl[buf];  // B-operand (C cols)
#pragma unroll
    for (int ksl = 0; ksl < 2; ksl++) {
      f16x8 af[4], bf[2];
#pragma unroll
      for (int i = 0; i < 4; i++)
        af[i] = *(const f16x8*)&Ra[((wr * 4 + i) * 2 + ksl) * 512 + lane * 8];
#pragma unroll
      for (int j = 0; j < 2; j++)
        bf[j] = *(const f16x8*)&Cb[((xc * 2 + j) * 2 + ksl) * 512 + lane * 8];
#pragma unroll
      for (int i = 0; i < 4; i++)
#pragma unroll
        for (int j = 0; j < 2; j++) acc[i][j] = MFMA_F16(af[i], bf[j], acc[i][j]);
    }
    __syncthreads();
    if (t + 2 < 4) QISSUE(t + 2, buf);
  }

  if (z < 2) {
    // C rows = hd (k-runs over r), cols = seq -> Q/K packed chunks.
    // K (z==1): seq slot permuted: slot' = pi^-1(kv6).
#pragma unroll
    for (int i = 0; i < 4; i++) {
      const int k0h = wr * 64 + i * 16 + quad * 4;
      float4 bq = *(const float4*)(bias + h * 128 + k0h);
      const int ks2 = k0h >> 5, q2 = (k0h >> 3) & 3, lo = k0h & 7;
#pragma unroll
      for (int j = 0; j < 2; j++) {
        const int bn2 = xt * 128 + xc * 32 + j * 16 + col;
        const int b = bn2 >> 10, n2 = bn2 & 1023;
        const int T = n2 >> 6;
        int jt, c2;
        if (z == 1) {
          jt = 2 * ((n2 >> 5) & 1) + ((n2 >> 2) & 1);
          c2 = ((n2 >> 3) & 3) * 4 + (n2 & 3);
        } else {
          jt = (n2 >> 4) & 3;
          c2 = n2 & 15;
        }
        f16x4 pk;
#pragma unroll
        for (int r = 0; r < 4; r++)
          pk[r] = (f16)((acc[i][j][r] + ((const float*)&bq)[r]) * sc);
        *(f16x4*)(outp + (size_t)(b * 8 + h) * 131072 + T * 8192 +
                  (jt * 4 + ks2) * 512 + (q2 * 16 + c2) * 8 + lo) = pk;
      }
    }
  } else {
#pragma unroll
    for (int j = 0; j < 2; j++) {
      const int d = xc * 32 + j * 16 + col;
      const float bv = bias[h * 128 + d];
      const int ct = d >> 4, cc = d & 15;
#pragma unroll
      for (int i = 0; i < 4; i++) {
        const int bn2 = xt * 128 + wr * 64 + i * 16 + quad * 4;
        const int b = bn2 >> 10, n2 = bn2 & 1023;
        const int T = n2 >> 6, kv6 = n2 & 63;
        const int ks2 = kv6 >> 5, qv = (kv6 >> 3) & 3, jj = kv6 & 7;
        f16x4 pk;
#pragma unroll
        for (int r = 0; r < 4; r++) pk[r] = (f16)(acc[i][j][r] + bv);
        *(f16x4*)(outp + (size_t)(b * 8 + h) * 131072 + T * 8192 +
                  (ct * 2 + ks2) * 512 + (qv * 16 + cc) * 8 + jj) = pk;
      }
    }
  }
}

// ---------------------------------------------------------------------------
// Proj GEMM: out[16384,128] = A[16384,1024](f16) @ W[128,1024]^T + b, fp32.
// ---------------------------------------------------------------------------
__global__ __launch_bounds__(256) void gemm_proj(const f16* __restrict__ A,
                                                 const float* __restrict__ W,
                                                 const float* __restrict__ bias,
                                                 float* __restrict__ out) {
  constexpr int LD = 72;
  __shared__ f16 As[64][LD];
  __shared__ f16 Bs[64][LD];
  const int tid = threadIdx.x, lane = tid & 63, wid = tid >> 6;
  const int col = lane & 15, quad = lane >> 4;
  const int wm = (wid >> 1) * 32, wn = (wid & 1) * 32;
  const int m0 = blockIdx.x * 64, n0 = blockIdx.y * 64;

  f32x4 acc[2][2];
#pragma unroll
  for (int i = 0; i < 2; i++)
#pragma unroll
    for (int j = 0; j < 2; j++) acc[i][j] = (f32x4){0.f, 0.f, 0.f, 0.f};

  for (int kt = 0; kt < 16; ++kt) {
    const int k0 = kt * 64;
#pragma unroll
    for (int i = 0; i < 2; i++) {
      int f = i * 256 + tid;
      int r = f >> 3, ch = f & 7;
      *(f16x8*)&As[r][ch * 8] = *(const f16x8*)(A + (size_t)(m0 + r) * 1024 + k0 + ch * 8);
    }
#pragma unroll
    for (int i = 0; i < 4; i++) {
      int f = i * 256 + tid;
      int r = f >> 4, c4 = f & 15;
      float4 v = *(const float4*)(W + (size_t)(n0 + r) * 1024 + k0 + c4 * 4);
      f16x4 hh; hh[0] = (f16)v.x; hh[1] = (f16)v.y; hh[2] = (f16)v.z; hh[3] = (f16)v.w;
      *(f16x4*)&Bs[r][c4 * 4] = hh;
    }
    __syncthreads();
#pragma unroll
    for (int ks = 0; ks < 2; ks++) {
      f16x8 af[2], bf[2];
#pragma unroll
      for (int i = 0; i < 2; i++) af[i] = *(const f16x8*)&As[wm + i * 16 + col][ks * 32 + quad * 8];
#pragma unroll
      for (int j = 0; j < 2; j++) bf[j] = *(const f16x8*)&Bs[wn + j * 16 + col][ks * 32 + quad * 8];
#pragma unroll
      for (int i = 0; i < 2; i++)
#pragma unroll
        for (int j = 0; j < 2; j++) acc[i][j] = MFMA_F16(af[i], bf[j], acc[i][j]);
    }
    __syncthreads();
  }
#pragma unroll
  for (int j = 0; j < 2; j++) {
    const int c = n0 + wn + j * 16 + col;
    const float bv = bias[c];
#pragma unroll
    for (int i = 0; i < 2; i++) {
      const int r0 = m0 + wm + i * 16 + quad * 4;
#pragma unroll
      for (int r = 0; r < 4; r++)
        out[(size_t)(r0 + r) * 128 + c] = acc[i][j][r] + bv;
    }
  }
}

// ---------------------------------------------------------------------------
// Fused attention v12 (R14): 512 thr = 8 waves x 32 q-rows = 256 q-rows/block,
// kv-tile 64, gl_lds double-buffer, Eb f16 exp-bias, NO Ps (K-perm in-reg P).
// launch_bounds(512,2): 256-VGPR cap (R13's waves_per_eu(4) forced 128-cap
// megaspill). LDS 64KB; 1 block/CU expected (VGPR ~170 > 128).
// ---------------------------------------------------------------------------
__global__ __launch_bounds__(512, 2)
void attn_fused(const f16* __restrict__ Qp, const f16* __restrict__ Kp,
                const f16* __restrict__ Vp, const f16* __restrict__ Ebp,
                f16* __restrict__ O) {
  __shared__ f16 Ksl[2][8192];
  __shared__ f16 Vtl[2][8192];
  const int tid = threadIdx.x, lane = tid & 63, wid = tid >> 6;  // wid 0..7
  const int col = lane & 15, quad = lane >> 4;
  const int id = blockIdx.x;
  const int mt = (id >> 3) & 3;                       // 4 m-tiles of 256 rows
  const int bh = ((id >> 5) << 3) | (id & 7);         // b = id>>5, h = id&7
  const int b = bh >> 3, h = bh & 7;
  const int m0 = mt * 256;
  const int wm = wid * 32;  // wave's 32 q-rows within the 256-row tile

  const f16* Qb = Qp + (size_t)bh * 131072;
  const f16* Kb = Kp + (size_t)bh * 131072;
  const f16* Vb = Vp + (size_t)bh * 131072;
  // Eb base: 128-row tile index = mt*2 + (wid>>2); qcw = (wid&3)*2 + qc.
  const int tile128 = mt * 2 + (wid >> 2);
  const f16* Ebw = Ebp +
      (((size_t)tile128 * 16 * 8 + (wid & 3) * 2) * 2) * 512 + lane * 8;

  // waves 0-3 stage K chunks (4 each), waves 4-7 stage V chunks (4 each)
#define AISSUE(T, bufi)                                                       \
  {                                                                           \
    if (wid < 4) {                                                            \
      _Pragma("unroll") for (int j = 0; j < 4; j++)                           \
          gl_lds16(Kb + (size_t)(T) * 8192 + (wid * 4 + j) * 512 + lane * 8,  \
                   &Ksl[bufi][(wid * 4 + j) * 512]);                          \
    } else {                                                                  \
      _Pragma("unroll") for (int j = 0; j < 4; j++)                           \
          gl_lds16(Vb + (size_t)(T) * 8192 + ((wid - 4) * 4 + j) * 512 + lane * 8, \
                   &Vtl[bufi][((wid - 4) * 4 + j) * 512]);                    \
    }                                                                         \
  }

  AISSUE(0, 0);
  AISSUE(1, 1);

  f16x8 qf[2][4];
#pragma unroll
  for (int qc = 0; qc < 2; qc++) {
    const int m = m0 + wm + qc * 16;
    const int T = m >> 6, jt2 = (m >> 4) & 3;
#pragma unroll
    for (int ks = 0; ks < 4; ks++)
      qf[qc][ks] = *(const f16x8*)(Qb + T * 8192 + (jt2 * 4 + ks) * 512 + lane * 8);
  }

  f32x4 oacc[2][8];
  float l[2] = {0.f, 0.f};
#pragma unroll
  for (int qc = 0; qc < 2; qc++)
#pragma unroll
    for (int ct = 0; ct < 8; ct++) oacc[qc][ct] = (f32x4){0.f, 0.f, 0.f, 0.f};

  __syncthreads();

  for (int t = 0; t < 16; ++t) {
    const int buf = t & 1;

    // exp-bias: 4 lane-contiguous f16x8 loads (16B lane stride)
    f16x8 ebA[2], ebB[2];
    {
      const f16* Et = Ebw + (size_t)t * 8192;
      ebA[0] = *(const f16x8*)(Et);
      ebB[0] = *(const f16x8*)(Et + 512);
      ebA[1] = *(const f16x8*)(Et + 1024);
      ebB[1] = *(const f16x8*)(Et + 1536);
    }

    f32x4 s[2][4];
#pragma unroll
    for (int qc = 0; qc < 2; qc++)
#pragma unroll
      for (int jt = 0; jt < 4; jt++) s[qc][jt] = (f32x4){0.f, 0.f, 0.f, 0.f};
#pragma unroll
    for (int ks = 0; ks < 4; ks++) {
      f16x8 kf[4];
#pragma unroll
      for (int jt = 0; jt < 4; jt++)
        kf[jt] = *(const f16x8*)&Ksl[buf][(jt * 4 + ks) * 512 + lane * 8];
#pragma unroll
      for (int jt = 0; jt < 4; jt++)
#pragma unroll
        for (int qc = 0; qc < 2; qc++)
          s[qc][jt] = MFMA_F16(kf[jt], qf[qc][ks], s[qc][jt]);
    }

    // softmax numerator straight into PV A-fragments (K-perm: s[jt][r] is
    // actual kv (jt>>1)*32 + quad*8 + (jt&1)*4 + r).
    f16x8 pa[2][2];   // [qc][ks]: P[q=col][kv = ks*32 + quad*8 + 0..7]
#pragma unroll
    for (int qc = 0; qc < 2; qc++) {
#pragma unroll
      for (int jt = 0; jt < 4; jt++) {
        float p0, p1, p2, p3;
        if (jt < 2) {
          p0 = __expf(s[qc][jt][0]) * (float)ebA[qc][(jt & 1) * 4 + 0];
          p1 = __expf(s[qc][jt][1]) * (float)ebA[qc][(jt & 1) * 4 + 1];
          p2 = __expf(s[qc][jt][2]) * (float)ebA[qc][(jt & 1) * 4 + 2];
          p3 = __expf(s[qc][jt][3]) * (float)ebA[qc][(jt & 1) * 4 + 3];
        } else {
          p0 = __expf(s[qc][jt][0]) * (float)ebB[qc][(jt & 1) * 4 + 0];
          p1 = __expf(s[qc][jt][1]) * (float)ebB[qc][(jt & 1) * 4 + 1];
          p2 = __expf(s[qc][jt][2]) * (float)ebB[qc][(jt & 1) * 4 + 2];
          p3 = __expf(s[qc][jt][3]) * (float)ebB[qc][(jt & 1) * 4 + 3];
        }
        l[qc] += (p0 + p1) + (p2 + p3);
        f16x4 pk; pk[0] = (f16)p0; pk[1] = (f16)p1; pk[2] = (f16)p2; pk[3] = (f16)p3;
        ((f16x4*)&pa[qc][jt >> 1])[jt & 1] = pk;   // static idx (unrolled)
      }
    }

#pragma unroll
    for (int ks = 0; ks < 2; ks++) {
#pragma unroll
      for (int ct = 0; ct < 8; ct++) {
        f16x8 vf = *(const f16x8*)&Vtl[buf][(ct * 2 + ks) * 512 + lane * 8];
#pragma unroll
        for (int qc = 0; qc < 2; qc++)
          oacc[qc][ct] = MFMA_F16(pa[qc][ks], vf, oacc[qc][ct]);
      }
    }

    __syncthreads();
    if (t + 2 < 16) AISSUE(t + 2, buf);
  }

#pragma unroll
  for (int qc = 0; qc < 2; qc++) {
    float lw = l[qc];
    lw += __shfl_xor(lw, 16);
    lw += __shfl_xor(lw, 32);
    f16* Ob = O + ((size_t)(b * 1024 + m0 + wm + qc * 16)) * 1024 + h * 128;
#pragma unroll
    for (int r = 0; r < 4; r++) {
      const float lv = __shfl(lw, (lane & 48) | (quad * 4 + r));
      const float inv = 1.0f / lv;
#pragma unroll
      for (int ct = 0; ct < 8; ct++)
        Ob[(size_t)(quad * 4 + r) * 1024 + ct * 16 + col] = (f16)(oacc[qc][ct][r] * inv);
    }
  }
}

extern "C" void kernel_launch(void* const* d_in, const int* in_sizes, int n_in,
                              void* d_out, int out_size, void* d_ws, size_t ws_size,
                              hipStream_t stream) {
  (void)in_sizes; (void)n_in; (void)out_size; (void)ws_size;
  const float* x1  = (const float*)d_in[0];
  const float* x2  = (const float*)d_in[1];
  const float* Bm  = (const float*)d_in[2];
  const float* wq  = (const float*)d_in[3];
  const float* wqb = (const float*)d_in[4];
  const float* wk  = (const float*)d_in[5];
  const float* wkb = (const float*)d_in[6];
  const float* wv  = (const float*)d_in[7];
  const float* wvb = (const float*)d_in[8];
  const float* pw  = (const float*)d_in[9];
  const float* pb  = (const float*)d_in[10];
  float* out = (float*)d_out;

  const size_t MiB = 1024 * 1024;
  f16* Qp  = (f16*)d_ws;                            // 0..32 MiB
  f16* Kp  = (f16*)((char*)d_ws + 32 * MiB);        // 32..64
  f16* Vp  = (f16*)((char*)d_ws + 64 * MiB);        // 64..96
  f16* Ow  = (f16*)((char*)d_ws + 96 * MiB);        // 96..128 (attn output)
  // packed inputs: alive only conv->qkv, then overlaid by Ow
  f16* x1p = (f16*)((char*)d_ws + 96 * MiB);        // 8 MiB
  f16* x2p = (f16*)((char*)d_ws + 104 * MiB);       // 8 MiB
  f16* wp  = (f16*)((char*)d_ws + 112 * MiB);       // 1.5 MiB
  // Packed exp-bias in d_out's first 2 MiB (out is 8 MiB fp32): written by
  // pack_eb pre-attn, read by attn, overwritten by gemm_proj at the end.
  f16* Ebp = (f16*)d_out;

  const float scale = 0.0883883476483184f;  // 1/sqrt(128)
  conv_pack<<<dim3(280), dim3(256), 0, stream>>>(x1, x2, wq, wk, wv, x1p, x2p, wp);
  pack_eb<<<dim3(128), dim3(256), 0, stream>>>(Bm, Ebp);
  gemm_qkv<<<dim3(128, 8, 3), dim3(512), 0, stream>>>(x1p, x2p, wp, wqb, wkb, wvb,
                                                      Qp, Kp, Vp, scale);
  attn_fused<<<dim3(512), dim3(512), 0, stream>>>(Qp, Kp, Vp, Ebp, Ow);
  gemm_proj<<<dim3(256, 2), dim3(256), 0, stream>>>(Ow, pw, pb, out);
}